// Round 1
// baseline (636.882 us; speedup 1.0000x reference)
//
#include <hip/hip_runtime.h>
#include <math.h>

typedef unsigned short u16;
typedef unsigned int u32;
typedef __attribute__((ext_vector_type(4))) float f32x4;
typedef __attribute__((ext_vector_type(8))) __bf16 bf16x8;

#define B_ 4
#define T_ 2048
#define D_ 1024
#define H_ 16
#define HD_ 64

// ---------- helpers ----------
__device__ __forceinline__ u16 f2b_rne(float f) {
  u32 u = __float_as_uint(f);
  u32 r = (u + 0x7FFFu + ((u >> 16) & 1u)) >> 16;
  return (u16)r;
}
__device__ __forceinline__ float b2f(u16 u) {
  return __uint_as_float(((u32)u) << 16);
}
__device__ __forceinline__ void gload_lds16(const void* g, void* l) {
  __builtin_amdgcn_global_load_lds(
      (const __attribute__((address_space(1))) u32*)g,
      (__attribute__((address_space(3))) u32*)l, 16, 0, 0);
}

// ---------- fp32 -> bf16 convert ----------
__global__ void f2b_kernel(const float* __restrict__ in, u16* __restrict__ out, int n) {
  int i = blockIdx.x * 256 + threadIdx.x;
  if (i < n) out[i] = f2b_rne(in[i]);
}

// ---------- RoPE + scatter to (B,H,T,hd) for Q,K and (B,H,hd,T) for V ----------
__global__ void rope_scatter_kernel(const u16* __restrict__ qkv,
                                    u16* __restrict__ Q, u16* __restrict__ K,
                                    u16* __restrict__ VT) {
  int j = blockIdx.x * 256 + threadIdx.x;
  if (j >= (B_ * T_) * (D_ / 2)) return;
  int row = j >> 9;              // b*T + t, 0..8191
  int p = j & 511;               // pair id in row
  int h = p >> 5, i = p & 31;    // head, rot index
  int b = row >> 11, t = row & (T_ - 1);
  const u16* base = qkv + (size_t)row * (3 * D_);
  // inv_freq = 10000^(-i/32) = 2^(-i*log2(10000)/32)
  float inv_freq = exp2f(-(float)i * 0.4152410118609203f);
  float ang = (float)t * inv_freq;
  float s, c;
  sincosf(ang, &s, &c);
  int qi = h * HD_ + i;
  float q1 = b2f(base[qi]),        q2 = b2f(base[qi + 32]);
  float k1 = b2f(base[D_ + qi]),   k2 = b2f(base[D_ + qi + 32]);
  u16   v1 = base[2 * D_ + qi],    v2 = base[2 * D_ + qi + 32];
  // fold softmax 1/sqrt(64) into q (exact in bf16: power of two)
  float qo1 = (q1 * c - q2 * s) * 0.125f;
  float qo2 = (q2 * c + q1 * s) * 0.125f;
  float ko1 = k1 * c - k2 * s;
  float ko2 = k2 * c + k1 * s;
  size_t bh = (size_t)(b * H_ + h);
  size_t qk = bh * T_ * HD_ + (size_t)t * HD_ + i;
  Q[qk]      = f2b_rne(qo1);
  Q[qk + 32] = f2b_rne(qo2);
  K[qk]      = f2b_rne(ko1);
  K[qk + 32] = f2b_rne(ko2);
  size_t vt = bh * (size_t)HD_ * T_ + (size_t)i * T_ + t;
  VT[vt]            = v1;
  VT[vt + 32 * T_]  = v2;
}

// ---------- bf16 GEMM, C = A(MxK) @ B(NxK)^T + bias, m97-style 128x128 tile ----------
template <bool F32OUT>
__global__ __launch_bounds__(256) void gemm_bt_kernel(
    const u16* __restrict__ A, const u16* __restrict__ Bm,
    const float* __restrict__ bias, void* __restrict__ Cout,
    int M, int N, int K) {
  __shared__ __align__(16) u16 As[128 * 64];
  __shared__ __align__(16) u16 Bs[128 * 64];
  const int tid = threadIdx.x;
  const int wid = tid >> 6, lane = tid & 63;
  const int l15 = lane & 15, lhi = lane >> 4;
  const int brow = blockIdx.x, bcol = blockIdx.y;
  const int wr = wid >> 1, wc = wid & 1;

  f32x4 acc[4][4] = {};

  for (int k0 = 0; k0 < K; k0 += 64) {
#pragma unroll
    for (int cc = 0; cc < 4; cc++) {
      int chunk = cc * 4 + wid;          // 16 chunks of 1KB per tile
      int slot = chunk * 64 + lane;      // 16B slots
      int row = slot >> 3;               // 8 slots per 128B row
      int colb = (slot & 7) << 4;        // byte within row
      gload_lds16((const char*)(A + (size_t)(brow * 128 + row) * K + k0) + colb,
                  (char*)As + chunk * 1024);
      gload_lds16((const char*)(Bm + (size_t)(bcol * 128 + row) * K + k0) + colb,
                  (char*)Bs + chunk * 1024);
    }
    __syncthreads();
#pragma unroll
    for (int kk = 0; kk < 2; kk++) {
      bf16x8 af[4], bfr[4];
#pragma unroll
      for (int i = 0; i < 4; i++)
        af[i] = *(const bf16x8*)&As[(wr * 64 + i * 16 + l15) * 64 + kk * 32 + lhi * 8];
#pragma unroll
      for (int j = 0; j < 4; j++)
        bfr[j] = *(const bf16x8*)&Bs[(wc * 64 + j * 16 + l15) * 64 + kk * 32 + lhi * 8];
#pragma unroll
      for (int i = 0; i < 4; i++)
#pragma unroll
        for (int j = 0; j < 4; j++)
          acc[i][j] = __builtin_amdgcn_mfma_f32_16x16x32_bf16(af[i], bfr[j], acc[i][j], 0, 0, 0);
    }
    __syncthreads();
  }
#pragma unroll
  for (int i = 0; i < 4; i++)
#pragma unroll
    for (int r = 0; r < 4; r++) {
      int row = brow * 128 + wr * 64 + i * 16 + lhi * 4 + r;
#pragma unroll
      for (int j = 0; j < 4; j++) {
        int col = bcol * 128 + wc * 64 + j * 16 + l15;
        float v = acc[i][j][r] + bias[col];
        if (F32OUT)
          ((float*)Cout)[(size_t)row * N + col] = v;
        else
          ((u16*)Cout)[(size_t)row * N + col] = f2b_rne(v);
      }
    }
}

// ---------- causal flash attention ----------
// grid (T/64, B*H), 4 waves; wave w handles 16 q-rows. K layout (B,H,T,hd), V as VT (B,H,hd,T).
__global__ __launch_bounds__(256) void attn_kernel(
    const u16* __restrict__ Q, const u16* __restrict__ K,
    const u16* __restrict__ VT, u16* __restrict__ O) {
  __shared__ __align__(16) u16 Plds[4][16][40];  // pad 32->40 to break conflicts
  const int tid = threadIdx.x;
  const int w = tid >> 6, lane = tid & 63;
  const int l15 = lane & 15, lhi = lane >> 4;
  const int q0 = blockIdx.x * 64;
  const int bh = blockIdx.y;
  const int bb = bh >> 4, hh = bh & 15;

  const u16* Qb = Q + (size_t)bh * T_ * HD_;
  const u16* Kb = K + (size_t)bh * T_ * HD_;
  const u16* Vb = VT + (size_t)bh * HD_ * T_;

  const int wrow0 = q0 + w * 16;
  const bf16x8 qf0 = *(const bf16x8*)&Qb[(size_t)(wrow0 + l15) * HD_ + lhi * 8];
  const bf16x8 qf1 = *(const bf16x8*)&Qb[(size_t)(wrow0 + l15) * HD_ + 32 + lhi * 8];

  float mrun[4], lrun[4];
  f32x4 oacc[4] = {};
#pragma unroll
  for (int r = 0; r < 4; r++) { mrun[r] = -1e30f; lrun[r] = 0.f; }

  const int nb = (wrow0 + 16 + 31) >> 5;  // causal: keys 0 .. wrow0+15
  for (int kb = 0; kb < nb; kb++) {
    const int t0 = kb * 32;
    f32x4 s0 = {0.f, 0.f, 0.f, 0.f}, s1 = {0.f, 0.f, 0.f, 0.f};
    {
      bf16x8 kf;
      kf = *(const bf16x8*)&Kb[(size_t)(t0 + l15) * HD_ + lhi * 8];
      s0 = __builtin_amdgcn_mfma_f32_16x16x32_bf16(qf0, kf, s0, 0, 0, 0);
      kf = *(const bf16x8*)&Kb[(size_t)(t0 + l15) * HD_ + 32 + lhi * 8];
      s0 = __builtin_amdgcn_mfma_f32_16x16x32_bf16(qf1, kf, s0, 0, 0, 0);
      kf = *(const bf16x8*)&Kb[(size_t)(t0 + 16 + l15) * HD_ + lhi * 8];
      s1 = __builtin_amdgcn_mfma_f32_16x16x32_bf16(qf0, kf, s1, 0, 0, 0);
      kf = *(const bf16x8*)&Kb[(size_t)(t0 + 16 + l15) * HD_ + 32 + lhi * 8];
      s1 = __builtin_amdgcn_mfma_f32_16x16x32_bf16(qf1, kf, s1, 0, 0, 0);
    }
    const int key0 = t0 + l15, key1 = t0 + 16 + l15;
#pragma unroll
    for (int r = 0; r < 4; r++) {
      const int grow = wrow0 + lhi * 4 + r;
      float a0 = (key0 <= grow) ? s0[r] : -1e30f;
      float a1 = (key1 <= grow) ? s1[r] : -1e30f;
      float mx = fmaxf(a0, a1);
      mx = fmaxf(mx, __shfl_xor(mx, 1));
      mx = fmaxf(mx, __shfl_xor(mx, 2));
      mx = fmaxf(mx, __shfl_xor(mx, 4));
      mx = fmaxf(mx, __shfl_xor(mx, 8));
      float mnew = fmaxf(mrun[r], mx);
      float corr = __expf(mrun[r] - mnew);
      float p0 = __expf(a0 - mnew);  // masked -> exp(-huge) = 0
      float p1 = __expf(a1 - mnew);
      float rs = p0 + p1;
      rs += __shfl_xor(rs, 1);
      rs += __shfl_xor(rs, 2);
      rs += __shfl_xor(rs, 4);
      rs += __shfl_xor(rs, 8);
      lrun[r] = lrun[r] * corr + rs;
      mrun[r] = mnew;
#pragma unroll
      for (int nd = 0; nd < 4; nd++) oacc[nd][r] *= corr;
      Plds[w][lhi * 4 + r][l15] = f2b_rne(p0);
      Plds[w][lhi * 4 + r][16 + l15] = f2b_rne(p1);
    }
    // per-wave LDS: compiler inserts lgkmcnt waits (may-alias, same wave)
    bf16x8 pa = *(const bf16x8*)&Plds[w][l15][lhi * 8];
#pragma unroll
    for (int nd = 0; nd < 4; nd++) {
      bf16x8 vf = *(const bf16x8*)&Vb[(size_t)(nd * 16 + l15) * T_ + t0 + lhi * 8];
      oacc[nd] = __builtin_amdgcn_mfma_f32_16x16x32_bf16(pa, vf, oacc[nd], 0, 0, 0);
    }
  }
#pragma unroll
  for (int r = 0; r < 4; r++) {
    float invl = 1.0f / lrun[r];
    int t = wrow0 + lhi * 4 + r;
    size_t ob = ((size_t)bb * T_ + t) * D_ + hh * HD_;
#pragma unroll
    for (int nd = 0; nd < 4; nd++)
      O[ob + nd * 16 + l15] = f2b_rne(oacc[nd][r] * invl);
  }
}

// ---------- launch ----------
extern "C" void kernel_launch(void* const* d_in, const int* in_sizes, int n_in,
                              void* d_out, int out_size, void* d_ws, size_t ws_size,
                              hipStream_t stream) {
  const float* x  = (const float*)d_in[0];
  const float* Wq = (const float*)d_in[1];
  const float* bq = (const float*)d_in[2];
  const float* Wk = (const float*)d_in[3];
  const float* bk = (const float*)d_in[4];
  const float* Wv = (const float*)d_in[5];
  const float* bv = (const float*)d_in[6];
  const float* Wo = (const float*)d_in[7];
  const float* bo = (const float*)d_in[8];

  char* ws = (char*)d_ws;
  // layout (bytes): xb 16.78M | qkv 50.33M | q 16.78M | k 16.78M | vt 16.78M | wqkv 6.29M | wo 2.10M | bqkv 12K
  u16*  XB    = (u16*)(ws + 0);            // also reused as attn output (dead after QKV GEMM)
  u16*  QKV   = (u16*)(ws + 16777216);
  u16*  Qb    = (u16*)(ws + 67108864);
  u16*  Kb    = (u16*)(ws + 83886080);
  u16*  VTb   = (u16*)(ws + 100663296);
  u16*  WQKVB = (u16*)(ws + 117440512);
  u16*  WOB   = (u16*)(ws + 123731968);
  float* BQKV = (float*)(ws + 125829120);
  u16*  ATTO  = XB;

  // bias concat [bq|bk|bv]
  hipMemcpyAsync(BQKV,        bq, D_ * 4, hipMemcpyDeviceToDevice, stream);
  hipMemcpyAsync(BQKV + D_,   bk, D_ * 4, hipMemcpyDeviceToDevice, stream);
  hipMemcpyAsync(BQKV + 2*D_, bv, D_ * 4, hipMemcpyDeviceToDevice, stream);

  // fp32 -> bf16
  f2b_kernel<<<32768, 256, 0, stream>>>(x, XB, B_ * T_ * D_);
  f2b_kernel<<<4096, 256, 0, stream>>>(Wq, WQKVB,               D_ * D_);
  f2b_kernel<<<4096, 256, 0, stream>>>(Wk, WQKVB + D_ * D_,     D_ * D_);
  f2b_kernel<<<4096, 256, 0, stream>>>(Wv, WQKVB + 2 * D_ * D_, D_ * D_);
  f2b_kernel<<<4096, 256, 0, stream>>>(Wo, WOB,                 D_ * D_);

  // QKV projection: (8192 x 1024) @ (3072 x 1024)^T + bias -> bf16
  gemm_bt_kernel<false><<<dim3(64, 24), 256, 0, stream>>>(
      XB, WQKVB, BQKV, QKV, B_ * T_, 3 * D_, D_);

  // RoPE + scatter
  rope_scatter_kernel<<<16384, 256, 0, stream>>>(QKV, Qb, Kb, VTb);

  // attention
  attn_kernel<<<dim3(T_ / 64, B_ * H_), 256, 0, stream>>>(Qb, Kb, VTb, ATTO);

  // output projection: (8192 x 1024) @ (1024 x 1024)^T + bo -> fp32 d_out
  gemm_bt_kernel<true><<<dim3(64, 8), 256, 0, stream>>>(
      ATTO, WOB, bo, d_out, B_ * T_, D_, D_);

  (void)in_sizes; (void)n_in; (void)out_size; (void)ws_size;
}

// Round 2
// 433.722 us; speedup vs baseline: 1.4684x; 1.4684x over previous
//
#include <hip/hip_runtime.h>
#include <math.h>

typedef unsigned short u16;
typedef unsigned int u32;
typedef __attribute__((ext_vector_type(4))) float f32x4;
typedef __attribute__((ext_vector_type(8))) __bf16 bf16x8;
typedef __attribute__((ext_vector_type(2))) __bf16 bf16x2;
typedef __attribute__((ext_vector_type(2))) u32 u32x2;

#define B_ 4
#define T_ 2048
#define D_ 1024
#define H_ 16
#define HD_ 64

// ---------- helpers ----------
__device__ __forceinline__ u16 f2b_rne(float f) {
  u32 u = __float_as_uint(f);
  u32 r = (u + 0x7FFFu + ((u >> 16) & 1u)) >> 16;
  return (u16)r;
}
__device__ __forceinline__ float b2f(u16 u) {
  return __uint_as_float(((u32)u) << 16);
}
__device__ __forceinline__ u32 pack2(float a, float b) {
  bf16x2 v = {(__bf16)a, (__bf16)b};  // hw v_cvt_pk_bf16_f32 (RNE)
  return __builtin_bit_cast(u32, v);
}
__device__ __forceinline__ void gload_lds16(const void* g, void* l) {
  __builtin_amdgcn_global_load_lds(
      (const __attribute__((address_space(1))) u32*)g,
      (__attribute__((address_space(3))) u32*)l, 16, 0, 0);
}

// ---------- fp32 -> bf16 convert, 4 elems/thread ----------
__global__ void f2b4_kernel(const float* __restrict__ in, u16* __restrict__ out, int n4) {
  int i = blockIdx.x * 256 + threadIdx.x;
  if (i < n4) {
    f32x4 v = ((const f32x4*)in)[i];
    u32x2 o;
    o.x = pack2(v[0], v[1]);
    o.y = pack2(v[2], v[3]);
    ((u32x2*)out)[i] = o;
  }
}

// ---------- RoPE + scatter to (B,H,T,hd) for Q,K and (B,H,hd,T) for V ----------
__global__ void rope_scatter_kernel(const u16* __restrict__ qkv,
                                    u16* __restrict__ Q, u16* __restrict__ K,
                                    u16* __restrict__ VT) {
  int j = blockIdx.x * 256 + threadIdx.x;
  if (j >= (B_ * T_) * (D_ / 2)) return;
  int row = j >> 9;              // b*T + t, 0..8191
  int p = j & 511;               // pair id in row
  int h = p >> 5, i = p & 31;    // head, rot index
  int b = row >> 11, t = row & (T_ - 1);
  const u16* base = qkv + (size_t)row * (3 * D_);
  float inv_freq = exp2f(-(float)i * 0.4152410118609203f);
  float ang = (float)t * inv_freq;
  float s, c;
  sincosf(ang, &s, &c);
  int qi = h * HD_ + i;
  float q1 = b2f(base[qi]),        q2 = b2f(base[qi + 32]);
  float k1 = b2f(base[D_ + qi]),   k2 = b2f(base[D_ + qi + 32]);
  u16   v1 = base[2 * D_ + qi],    v2 = base[2 * D_ + qi + 32];
  float qo1 = (q1 * c - q2 * s) * 0.125f;  // fold 1/sqrt(64) into q
  float qo2 = (q2 * c + q1 * s) * 0.125f;
  float ko1 = k1 * c - k2 * s;
  float ko2 = k2 * c + k1 * s;
  size_t bh = (size_t)(b * H_ + h);
  size_t qk = bh * T_ * HD_ + (size_t)t * HD_ + i;
  Q[qk]      = f2b_rne(qo1);
  Q[qk + 32] = f2b_rne(qo2);
  K[qk]      = f2b_rne(ko1);
  K[qk + 32] = f2b_rne(ko2);
  size_t vt = bh * (size_t)HD_ * T_ + (size_t)i * T_ + t;
  VT[vt]            = v1;
  VT[vt + 32 * T_]  = v2;
}

// ---------- bf16 GEMM, C = A(MxK) @ B(NxK)^T + bias, m97-style 128x128 tile ----------
template <bool F32OUT>
__global__ __launch_bounds__(256) void gemm_bt_kernel(
    const u16* __restrict__ A, const u16* __restrict__ Bm,
    const float* __restrict__ bias, void* __restrict__ Cout,
    int M, int N, int K) {
  __shared__ __align__(16) u16 As[128 * 64];
  __shared__ __align__(16) u16 Bs[128 * 64];
  const int tid = threadIdx.x;
  const int wid = tid >> 6, lane = tid & 63;
  const int l15 = lane & 15, lhi = lane >> 4;
  const int brow = blockIdx.x, bcol = blockIdx.y;
  const int wr = wid >> 1, wc = wid & 1;

  f32x4 acc[4][4] = {};

  for (int k0 = 0; k0 < K; k0 += 64) {
#pragma unroll
    for (int cc = 0; cc < 4; cc++) {
      int chunk = cc * 4 + wid;
      int slot = chunk * 64 + lane;
      int row = slot >> 3;
      int colb = (slot & 7) << 4;
      gload_lds16((const char*)(A + (size_t)(brow * 128 + row) * K + k0) + colb,
                  (char*)As + chunk * 1024);
      gload_lds16((const char*)(Bm + (size_t)(bcol * 128 + row) * K + k0) + colb,
                  (char*)Bs + chunk * 1024);
    }
    __syncthreads();
#pragma unroll
    for (int kk = 0; kk < 2; kk++) {
      bf16x8 af[4], bfr[4];
#pragma unroll
      for (int i = 0; i < 4; i++)
        af[i] = *(const bf16x8*)&As[(wr * 64 + i * 16 + l15) * 64 + kk * 32 + lhi * 8];
#pragma unroll
      for (int j = 0; j < 4; j++)
        bfr[j] = *(const bf16x8*)&Bs[(wc * 64 + j * 16 + l15) * 64 + kk * 32 + lhi * 8];
#pragma unroll
      for (int i = 0; i < 4; i++)
#pragma unroll
        for (int j = 0; j < 4; j++)
          acc[i][j] = __builtin_amdgcn_mfma_f32_16x16x32_bf16(af[i], bfr[j], acc[i][j], 0, 0, 0);
    }
    __syncthreads();
  }
#pragma unroll
  for (int i = 0; i < 4; i++)
#pragma unroll
    for (int r = 0; r < 4; r++) {
      int row = brow * 128 + wr * 64 + i * 16 + lhi * 4 + r;
#pragma unroll
      for (int j = 0; j < 4; j++) {
        int col = bcol * 128 + wc * 64 + j * 16 + l15;
        float v = acc[i][j][r] + bias[col];
        if (F32OUT)
          ((float*)Cout)[(size_t)row * N + col] = v;
        else
          ((u16*)Cout)[(size_t)row * N + col] = f2b_rne(v);
      }
    }
}

// ---------- causal flash attention, swapped-operand in-register softmax ----------
// grid (T/64, B*H), 4 waves; wave w owns q rows q0+16w..+15. K (B,H,T,hd), V as VT (B,H,hd,T).
// Per lane: q-row = q0+16w+(lane&15), replicated over lane>>4 groups.
__global__ __launch_bounds__(256) void attn_kernel(
    const u16* __restrict__ Q, const u16* __restrict__ K,
    const u16* __restrict__ VT, u16* __restrict__ O) {
  __shared__ __align__(16) u16 Ks[2][64 * 64];   // 64 keys x 64 hd, XOR-swizzled rows
  __shared__ __align__(16) u16 Plds[4][16 * 72]; // per-wave P, row stride 72 u16
  const int tid = threadIdx.x;
  const int w = tid >> 6, lane = tid & 63;
  const int l15 = lane & 15, lhi = lane >> 4;
  const int q0 = blockIdx.x * 64;
  const int bh = blockIdx.y;
  const int bb = bh >> 4, hh = bh & 15;

  const u16* Qb = Q + (size_t)bh * T_ * HD_;
  const u16* Kb = K + (size_t)bh * T_ * HD_;
  const u16* Vb = VT + (size_t)bh * HD_ * T_;

  const int qrow = q0 + w * 16 + l15;

  // Q B-fragment: Y[n=q=l15][k = c*32 + lhi*8 ..]
  const bf16x8 qf0 = *(const bf16x8*)&Qb[(size_t)qrow * HD_ + lhi * 8];
  const bf16x8 qf1 = *(const bf16x8*)&Qb[(size_t)qrow * HD_ + 32 + lhi * 8];

  float mrun = -1e30f, lrun = 0.f;
  f32x4 oacc[4] = {};

  const int nb = q0 / 64 + 1;  // causal: tiles of 64 keys, last one masked

  // stage K tile: 64 rows x 128B, swizzle byte ^= (row&7)<<4, via pre-swizzled src
  auto stage = [&](int buf, int t0) {
#pragma unroll
    for (int p = 0; p < 2; p++) {
      int idx = p * 256 + tid;
      int row = idx >> 3, slot = idx & 7;
      int srcb = (slot << 4) ^ ((row & 7) << 4);
      gload_lds16((const char*)(Kb + (size_t)(t0 + row) * HD_) + srcb,
                  (char*)&Ks[buf][0] + (p * 256 + w * 64) * 16);  // uniform base + lane*16
    }
  };

  stage(0, 0);
  __syncthreads();

  int buf = 0;
  for (int t = 0; t < nb; t++) {
    const int t0 = t * 64;
    if (t + 1 < nb) stage(buf ^ 1, t0 + 64);  // prefetch next tile (drains at barrier)

    // QK^T swapped: s[ks] lane(l15,lhi) reg r = S(key=t0+16ks+4lhi+r, q=qrow)
    f32x4 s[4];
#pragma unroll
    for (int ks = 0; ks < 4; ks++) {
      const char* base = (const char*)&Ks[buf][0] + (ks * 16 + l15) * 128;
      int sw = (l15 & 7) << 4;
      bf16x8 kf0 = *(const bf16x8*)(base + ((lhi * 16) ^ sw));
      bf16x8 kf1 = *(const bf16x8*)(base + ((64 + lhi * 16) ^ sw));
      f32x4 z = {0.f, 0.f, 0.f, 0.f};
      z = __builtin_amdgcn_mfma_f32_16x16x32_bf16(kf0, qf0, z, 0, 0, 0);
      s[ks] = __builtin_amdgcn_mfma_f32_16x16x32_bf16(kf1, qf1, z, 0, 0, 0);
    }

    // V^T A-fragments early: overlap L2 latency with softmax VALU
    bf16x8 vf[4][2];
#pragma unroll
    for (int db = 0; db < 4; db++)
#pragma unroll
      for (int c = 0; c < 2; c++)
        vf[db][c] = *(const bf16x8*)&Vb[(size_t)(db * 16 + l15) * T_ + t0 + c * 32 + lhi * 8];

    if (t == nb - 1) {  // wave-uniform branch: mask only the diagonal tile
#pragma unroll
      for (int ks = 0; ks < 4; ks++)
#pragma unroll
        for (int r = 0; r < 4; r++) {
          int key = t0 + ks * 16 + lhi * 4 + r;
          if (key > qrow) s[ks][r] = -1e30f;
        }
    }

    // in-register softmax: 16 values/lane + 2-shfl cross-group reduce
    float mx = s[0][0];
#pragma unroll
    for (int ks = 0; ks < 4; ks++)
#pragma unroll
      for (int r = 0; r < 4; r++) mx = fmaxf(mx, s[ks][r]);
    mx = fmaxf(mx, __shfl_xor(mx, 16));
    mx = fmaxf(mx, __shfl_xor(mx, 32));
    float mnew = fmaxf(mrun, mx);
    float corr = __expf(mrun - mnew);
    mrun = mnew;
    float p[16];
    float rs = 0.f;
#pragma unroll
    for (int ks = 0; ks < 4; ks++)
#pragma unroll
      for (int r = 0; r < 4; r++) {
        float e = __expf(s[ks][r] - mnew);
        p[ks * 4 + r] = e;
        rs += e;
      }
    rs += __shfl_xor(rs, 16);
    rs += __shfl_xor(rs, 32);
    lrun = lrun * corr + rs;
#pragma unroll
    for (int db = 0; db < 4; db++)
#pragma unroll
      for (int r = 0; r < 4; r++) oacc[db][r] *= corr;

    // pack P -> LDS [q=l15][key]; write 4 keys (8B) per ks
    u16* prow = &Plds[w][l15 * 72];
#pragma unroll
    for (int ks = 0; ks < 4; ks++) {
      u32x2 wv;
      wv.x = pack2(p[ks * 4 + 0], p[ks * 4 + 1]);
      wv.y = pack2(p[ks * 4 + 2], p[ks * 4 + 3]);
      *(u32x2*)&prow[ks * 16 + lhi * 4] = wv;
    }

    // PV swapped: oacc[db] = O^T block, D[m=d-in-block][n=q=l15]
#pragma unroll
    for (int c = 0; c < 2; c++) {
      bf16x8 pb = *(const bf16x8*)&prow[c * 32 + lhi * 8];  // P[q=l15][k=c*32+lhi*8..]
#pragma unroll
      for (int db = 0; db < 4; db++)
        oacc[db] = __builtin_amdgcn_mfma_f32_16x16x32_bf16(vf[db][c], pb, oacc[db], 0, 0, 0);
    }

    __syncthreads();
    buf ^= 1;
  }

  // epilogue: lane(l15,lhi) writes q-row qrow, d = db*16 + lhi*4 + r
  float invl = 1.0f / lrun;
  size_t ob = ((size_t)bb * T_ + qrow) * D_ + hh * HD_;
#pragma unroll
  for (int db = 0; db < 4; db++) {
    u32x2 wv;
    wv.x = pack2(oacc[db][0] * invl, oacc[db][1] * invl);
    wv.y = pack2(oacc[db][2] * invl, oacc[db][3] * invl);
    *(u32x2*)&O[ob + db * 16 + lhi * 4] = wv;
  }
}

// ---------- launch ----------
extern "C" void kernel_launch(void* const* d_in, const int* in_sizes, int n_in,
                              void* d_out, int out_size, void* d_ws, size_t ws_size,
                              hipStream_t stream) {
  const float* x  = (const float*)d_in[0];
  const float* Wq = (const float*)d_in[1];
  const float* bq = (const float*)d_in[2];
  const float* Wk = (const float*)d_in[3];
  const float* bk = (const float*)d_in[4];
  const float* Wv = (const float*)d_in[5];
  const float* bv = (const float*)d_in[6];
  const float* Wo = (const float*)d_in[7];
  const float* bo = (const float*)d_in[8];

  char* ws = (char*)d_ws;
  u16*  XB    = (u16*)(ws + 0);            // reused as attn output (dead after QKV GEMM)
  u16*  QKV   = (u16*)(ws + 16777216);
  u16*  Qb    = (u16*)(ws + 67108864);
  u16*  Kb    = (u16*)(ws + 83886080);
  u16*  VTb   = (u16*)(ws + 100663296);
  u16*  WQKVB = (u16*)(ws + 117440512);
  u16*  WOB   = (u16*)(ws + 123731968);
  float* BQKV = (float*)(ws + 125829120);
  u16*  ATTO  = XB;

  hipMemcpyAsync(BQKV,        bq, D_ * 4, hipMemcpyDeviceToDevice, stream);
  hipMemcpyAsync(BQKV + D_,   bk, D_ * 4, hipMemcpyDeviceToDevice, stream);
  hipMemcpyAsync(BQKV + 2*D_, bv, D_ * 4, hipMemcpyDeviceToDevice, stream);

  f2b4_kernel<<<8192, 256, 0, stream>>>(x, XB, B_ * T_ * D_ / 4);
  f2b4_kernel<<<1024, 256, 0, stream>>>(Wq, WQKVB,               D_ * D_ / 4);
  f2b4_kernel<<<1024, 256, 0, stream>>>(Wk, WQKVB + D_ * D_,     D_ * D_ / 4);
  f2b4_kernel<<<1024, 256, 0, stream>>>(Wv, WQKVB + 2 * D_ * D_, D_ * D_ / 4);
  f2b4_kernel<<<1024, 256, 0, stream>>>(Wo, WOB,                 D_ * D_ / 4);

  gemm_bt_kernel<false><<<dim3(64, 24), 256, 0, stream>>>(
      XB, WQKVB, BQKV, QKV, B_ * T_, 3 * D_, D_);

  rope_scatter_kernel<<<16384, 256, 0, stream>>>(QKV, Qb, Kb, VTb);

  attn_kernel<<<dim3(T_ / 64, B_ * H_), 256, 0, stream>>>(Qb, Kb, VTb, ATTO);

  gemm_bt_kernel<true><<<dim3(64, 8), 256, 0, stream>>>(
      ATTO, WOB, bo, d_out, B_ * T_, D_, D_);

  (void)in_sizes; (void)n_in; (void)out_size; (void)ws_size;
}

// Round 3
// 280.095 us; speedup vs baseline: 2.2738x; 1.5485x over previous
//
#include <hip/hip_runtime.h>
#include <math.h>

typedef unsigned short u16;
typedef unsigned int u32;
typedef __attribute__((ext_vector_type(4))) float f32x4;
typedef __attribute__((ext_vector_type(8))) __bf16 bf16x8;
typedef __attribute__((ext_vector_type(2))) __bf16 bf16x2;
typedef __attribute__((ext_vector_type(2))) u32 u32x2;

#define B_ 4
#define T_ 2048
#define D_ 1024
#define H_ 16
#define HD_ 64

// ---------- helpers ----------
__device__ __forceinline__ u16 f2b_rne(float f) {
  u32 u = __float_as_uint(f);
  u32 r = (u + 0x7FFFu + ((u >> 16) & 1u)) >> 16;
  return (u16)r;
}
__device__ __forceinline__ float b2f(u16 u) {
  return __uint_as_float(((u32)u) << 16);
}
__device__ __forceinline__ u32 pack2(float a, float b) {
  bf16x2 v = {(__bf16)a, (__bf16)b};  // hw v_cvt_pk_bf16_f32 (RNE)
  return __builtin_bit_cast(u32, v);
}
__device__ __forceinline__ void gload_lds16(const void* g, void* l) {
  __builtin_amdgcn_global_load_lds(
      (const __attribute__((address_space(1))) u32*)g,
      (__attribute__((address_space(3))) u32*)l, 16, 0, 0);
}

// ---------- fp32 -> bf16 convert, 4 elems/thread ----------
__global__ void f2b4_kernel(const float* __restrict__ in, u16* __restrict__ out, int n4) {
  int i = blockIdx.x * 256 + threadIdx.x;
  if (i < n4) {
    f32x4 v = ((const f32x4*)in)[i];
    u32x2 o;
    o.x = pack2(v[0], v[1]);
    o.y = pack2(v[2], v[3]);
    ((u32x2*)out)[i] = o;
  }
}

// ---------- RoPE for Q,K -> (B,H,T,hd); V handled by vt_kernel ----------
__global__ void rope_qk_kernel(const u16* __restrict__ qkv,
                               u16* __restrict__ Q, u16* __restrict__ K) {
  int j = blockIdx.x * 256 + threadIdx.x;
  if (j >= (B_ * T_) * (D_ / 2)) return;
  int row = j >> 9;              // b*T + t
  int p = j & 511;               // pair id in row
  int h = p >> 5, i = p & 31;    // head, rot index
  int b = row >> 11, t = row & (T_ - 1);
  const u16* base = qkv + (size_t)row * (3 * D_);
  float inv_freq = exp2f(-(float)i * 0.4152410118609203f);
  float ang = (float)t * inv_freq;
  float s, c;
  sincosf(ang, &s, &c);
  int qi = h * HD_ + i;
  float q1 = b2f(base[qi]),      q2 = b2f(base[qi + 32]);
  float k1 = b2f(base[D_ + qi]), k2 = b2f(base[D_ + qi + 32]);
  float qo1 = (q1 * c - q2 * s) * 0.125f;  // fold 1/sqrt(64) into q
  float qo2 = (q2 * c + q1 * s) * 0.125f;
  float ko1 = k1 * c - k2 * s;
  float ko2 = k2 * c + k1 * s;
  size_t bh = (size_t)(b * H_ + h);
  size_t qk = bh * T_ * HD_ + (size_t)t * HD_ + i;
  Q[qk]      = f2b_rne(qo1);
  Q[qk + 32] = f2b_rne(qo2);
  K[qk]      = f2b_rne(ko1);
  K[qk + 32] = f2b_rne(ko2);
}

// ---------- V transpose: qkv v-cols -> VT (B,H,hd,T), LDS 64x64 tile ----------
__global__ __launch_bounds__(256) void vt_kernel(const u16* __restrict__ qkv,
                                                 u16* __restrict__ VT) {
  __shared__ __align__(16) u16 tile[64 * 64];  // [i][t], byte ^= ((i>>3)<<4)
  const int x = blockIdx.x;   // t-tile
  const int bh = blockIdx.y;
  const int b = bh >> 4, h = bh & 15;
  const int tid = threadIdx.x;
  const u16* src = qkv + (size_t)(b * T_ + x * 64) * (3 * D_) + 2 * D_ + h * HD_;
#pragma unroll
  for (int it = 0; it < 2; ++it) {
    int r = it * 32 + (tid >> 3);       // t within tile
    int chunk = tid & 7;                // 8-elem chunk of hd
    bf16x8 v = *(const bf16x8*)(src + (size_t)r * (3 * D_) + chunk * 8);
    u16 tmp[8];
    *(bf16x8*)tmp = v;
#pragma unroll
    for (int jj = 0; jj < 8; ++jj) {
      int i = chunk * 8 + jj;
      int byte = i * 128 + ((2 * r) ^ ((i >> 3) << 4));
      *(u16*)((char*)tile + byte) = tmp[jj];
    }
  }
  __syncthreads();
  const int i = tid >> 2, tc = tid & 3;
  u16* dst = VT + (size_t)bh * HD_ * T_ + (size_t)i * T_ + x * 64 + tc * 16;
#pragma unroll
  for (int half = 0; half < 2; ++half) {
    int byte = i * 128 + ((tc * 32 + half * 16) ^ ((i >> 3) << 4));
    *(bf16x8*)(dst + half * 8) = *(const bf16x8*)((char*)tile + byte);
  }
}

// ---------- bf16 GEMM, C = A(MxK) @ B(NxK)^T + bias, m97-style 128x128 tile ----------
template <bool F32OUT>
__global__ __launch_bounds__(256) void gemm_bt_kernel(
    const u16* __restrict__ A, const u16* __restrict__ Bm,
    const float* __restrict__ bias, void* __restrict__ Cout,
    int M, int N, int K) {
  __shared__ __align__(16) u16 As[128 * 64];
  __shared__ __align__(16) u16 Bs[128 * 64];
  const int tid = threadIdx.x;
  const int wid = tid >> 6, lane = tid & 63;
  const int l15 = lane & 15, lhi = lane >> 4;
  const int brow = blockIdx.x, bcol = blockIdx.y;
  const int wr = wid >> 1, wc = wid & 1;

  f32x4 acc[4][4] = {};

  for (int k0 = 0; k0 < K; k0 += 64) {
#pragma unroll
    for (int cc = 0; cc < 4; cc++) {
      int chunk = cc * 4 + wid;
      int slot = chunk * 64 + lane;
      int row = slot >> 3;
      int colb = (slot & 7) << 4;
      gload_lds16((const char*)(A + (size_t)(brow * 128 + row) * K + k0) + colb,
                  (char*)As + chunk * 1024);
      gload_lds16((const char*)(Bm + (size_t)(bcol * 128 + row) * K + k0) + colb,
                  (char*)Bs + chunk * 1024);
    }
    __syncthreads();
#pragma unroll
    for (int kk = 0; kk < 2; kk++) {
      bf16x8 af[4], bfr[4];
#pragma unroll
      for (int i = 0; i < 4; i++)
        af[i] = *(const bf16x8*)&As[(wr * 64 + i * 16 + l15) * 64 + kk * 32 + lhi * 8];
#pragma unroll
      for (int j = 0; j < 4; j++)
        bfr[j] = *(const bf16x8*)&Bs[(wc * 64 + j * 16 + l15) * 64 + kk * 32 + lhi * 8];
#pragma unroll
      for (int i = 0; i < 4; i++)
#pragma unroll
        for (int j = 0; j < 4; j++)
          acc[i][j] = __builtin_amdgcn_mfma_f32_16x16x32_bf16(af[i], bfr[j], acc[i][j], 0, 0, 0);
    }
    __syncthreads();
  }
#pragma unroll
  for (int i = 0; i < 4; i++)
#pragma unroll
    for (int r = 0; r < 4; r++) {
      int row = brow * 128 + wr * 64 + i * 16 + lhi * 4 + r;
#pragma unroll
      for (int j = 0; j < 4; j++) {
        int col = bcol * 128 + wc * 64 + j * 16 + l15;
        float v = acc[i][j][r] + bias[col];
        if (F32OUT)
          ((float*)Cout)[(size_t)row * N + col] = v;
        else
          ((u16*)Cout)[(size_t)row * N + col] = f2b_rne(v);
      }
    }
}

// ---------- causal flash attention: barrier-free, QBLK=32/wave, KVBLK=64 ----------
// grid: 1024 blocks (heavy-first), 4 waves; wave w owns q rows q0+32w..+31 (2 sub-tiles of 16).
// K read direct from L2 (B,H,T,hd); V as VT (B,H,hd,T); P via per-wave swizzled LDS.
__global__ __launch_bounds__(256) void attn_kernel(
    const u16* __restrict__ Q, const u16* __restrict__ K,
    const u16* __restrict__ VT, u16* __restrict__ O) {
  __shared__ __align__(16) u16 Plds[4][2][16 * 64];  // [wave][qg][q=16 rows x 64 keys], swizzled
  const int tid = threadIdx.x;
  const int w = tid >> 6, lane = tid & 63;
  const int l15 = lane & 15, lhi = lane >> 4;
  const int bid = blockIdx.x;
  const int xq = 15 - (bid >> 6);   // heavy-first: big q-tiles scheduled first
  const int bh = bid & 63;
  const int q0 = xq * 128;
  const int bb = bh >> 4, hh = bh & 15;

  const u16* Qb = Q + (size_t)bh * T_ * HD_;
  const u16* Kb = K + (size_t)bh * T_ * HD_;
  const u16* Vb = VT + (size_t)bh * HD_ * T_;

  const int qbase = q0 + w * 32;

  // Q B-fragments: qf[g][c], q row = qbase + g*16 + l15
  bf16x8 qf[2][2];
#pragma unroll
  for (int g = 0; g < 2; ++g) {
    const u16* qr = Qb + (size_t)(qbase + g * 16 + l15) * HD_ + lhi * 8;
    qf[g][0] = *(const bf16x8*)(qr);
    qf[g][1] = *(const bf16x8*)(qr + 32);
  }

  float mrun[2] = {-1e30f, -1e30f}, lrun[2] = {0.f, 0.f};
  f32x4 oacc[2][4] = {};

  const int nb = (qbase + 95) >> 6;  // keys 0 .. qbase+31, 64-key tiles
  const int sw = (l15 & 7) << 4;

  for (int t = 0; t < nb; ++t) {
    const int t0 = t * 64;

    // QK^T swapped: s[g][ks] reg r = S(key=t0+16ks+4lhi+r, q=qbase+16g+l15)
    f32x4 s[2][4];
    const u16* Kt = Kb + (size_t)t0 * HD_;
#pragma unroll
    for (int ks = 0; ks < 4; ++ks) {
      const u16* kr = Kt + (size_t)(ks * 16 + l15) * HD_ + lhi * 8;
      bf16x8 kf0 = *(const bf16x8*)(kr);
      bf16x8 kf1 = *(const bf16x8*)(kr + 32);
#pragma unroll
      for (int g = 0; g < 2; ++g) {
        f32x4 z = {0.f, 0.f, 0.f, 0.f};
        z = __builtin_amdgcn_mfma_f32_16x16x32_bf16(kf0, qf[g][0], z, 0, 0, 0);
        s[g][ks] = __builtin_amdgcn_mfma_f32_16x16x32_bf16(kf1, qf[g][1], z, 0, 0, 0);
      }
    }

    // V^T A-fragments early: overlap L2 latency with softmax VALU
    bf16x8 vf[4][2];
#pragma unroll
    for (int db = 0; db < 4; ++db) {
      const u16* vr = Vb + (size_t)(db * 16 + l15) * T_ + t0 + lhi * 8;
      vf[db][0] = *(const bf16x8*)(vr);
      vf[db][1] = *(const bf16x8*)(vr + 32);
    }

    if (t == nb - 1) {  // wave-uniform: mask only the diagonal tile
#pragma unroll
      for (int g = 0; g < 2; ++g) {
        int qr = qbase + g * 16 + l15;
#pragma unroll
        for (int ks = 0; ks < 4; ++ks)
#pragma unroll
          for (int r = 0; r < 4; ++r)
            if (t0 + ks * 16 + lhi * 4 + r > qr) s[g][ks][r] = -1e30f;
      }
    }

    // in-register softmax per q-subtile: 16 vals/lane + 2-shfl cross-group reduce
#pragma unroll
    for (int g = 0; g < 2; ++g) {
      float mx = s[g][0][0];
#pragma unroll
      for (int ks = 0; ks < 4; ++ks)
#pragma unroll
        for (int r = 0; r < 4; ++r) mx = fmaxf(mx, s[g][ks][r]);
      mx = fmaxf(mx, __shfl_xor(mx, 16));
      mx = fmaxf(mx, __shfl_xor(mx, 32));
      float mnew = fmaxf(mrun[g], mx);
      float corr = __expf(mrun[g] - mnew);
      mrun[g] = mnew;
      float rs = 0.f;
      char* prow = (char*)&Plds[w][g][0] + l15 * 128;
#pragma unroll
      for (int ks = 0; ks < 4; ++ks) {
        float e0 = __expf(s[g][ks][0] - mnew);
        float e1 = __expf(s[g][ks][1] - mnew);
        float e2 = __expf(s[g][ks][2] - mnew);
        float e3 = __expf(s[g][ks][3] - mnew);
        rs += (e0 + e1) + (e2 + e3);
        u32x2 pw;
        pw.x = pack2(e0, e1);
        pw.y = pack2(e2, e3);
        *(u32x2*)(prow + ((ks * 32 + lhi * 8) ^ sw)) = pw;
      }
      rs += __shfl_xor(rs, 16);
      rs += __shfl_xor(rs, 32);
      lrun[g] = lrun[g] * corr + rs;
#pragma unroll
      for (int db = 0; db < 4; ++db)
#pragma unroll
        for (int r = 0; r < 4; ++r) oacc[g][db][r] *= corr;
    }

    // PV swapped: oacc[g][db] = O^T block
#pragma unroll
    for (int g = 0; g < 2; ++g) {
      const char* prow = (const char*)&Plds[w][g][0] + l15 * 128;
#pragma unroll
      for (int c = 0; c < 2; ++c) {
        bf16x8 pb = *(const bf16x8*)(prow + ((c * 64 + lhi * 16) ^ sw));
#pragma unroll
        for (int db = 0; db < 4; ++db)
          oacc[g][db] = __builtin_amdgcn_mfma_f32_16x16x32_bf16(vf[db][c], pb, oacc[g][db], 0, 0, 0);
      }
    }
  }

  // epilogue: lane (l15,lhi) writes q-row qbase+16g+l15, d = db*16 + lhi*4 + r
#pragma unroll
  for (int g = 0; g < 2; ++g) {
    float invl = 1.0f / lrun[g];
    int qr = qbase + g * 16 + l15;
    u16* orow = O + ((size_t)bb * T_ + qr) * D_ + hh * HD_ + lhi * 4;
#pragma unroll
    for (int db = 0; db < 4; ++db) {
      u32x2 wv;
      wv.x = pack2(oacc[g][db][0] * invl, oacc[g][db][1] * invl);
      wv.y = pack2(oacc[g][db][2] * invl, oacc[g][db][3] * invl);
      *(u32x2*)(orow + db * 16) = wv;
    }
  }
}

// ---------- launch ----------
extern "C" void kernel_launch(void* const* d_in, const int* in_sizes, int n_in,
                              void* d_out, int out_size, void* d_ws, size_t ws_size,
                              hipStream_t stream) {
  const float* x  = (const float*)d_in[0];
  const float* Wq = (const float*)d_in[1];
  const float* bq = (const float*)d_in[2];
  const float* Wk = (const float*)d_in[3];
  const float* bk = (const float*)d_in[4];
  const float* Wv = (const float*)d_in[5];
  const float* bv = (const float*)d_in[6];
  const float* Wo = (const float*)d_in[7];
  const float* bo = (const float*)d_in[8];

  char* ws = (char*)d_ws;
  u16*  XB    = (u16*)(ws + 0);            // reused as attn output (dead after QKV GEMM)
  u16*  QKV   = (u16*)(ws + 16777216);
  u16*  Qb    = (u16*)(ws + 67108864);
  u16*  Kb    = (u16*)(ws + 83886080);
  u16*  VTb   = (u16*)(ws + 100663296);
  u16*  WQKVB = (u16*)(ws + 117440512);
  u16*  WOB   = (u16*)(ws + 123731968);
  float* BQKV = (float*)(ws + 125829120);
  u16*  ATTO  = XB;

  hipMemcpyAsync(BQKV,        bq, D_ * 4, hipMemcpyDeviceToDevice, stream);
  hipMemcpyAsync(BQKV + D_,   bk, D_ * 4, hipMemcpyDeviceToDevice, stream);
  hipMemcpyAsync(BQKV + 2*D_, bv, D_ * 4, hipMemcpyDeviceToDevice, stream);

  f2b4_kernel<<<8192, 256, 0, stream>>>(x, XB, B_ * T_ * D_ / 4);
  f2b4_kernel<<<1024, 256, 0, stream>>>(Wq, WQKVB,               D_ * D_ / 4);
  f2b4_kernel<<<1024, 256, 0, stream>>>(Wk, WQKVB + D_ * D_,     D_ * D_ / 4);
  f2b4_kernel<<<1024, 256, 0, stream>>>(Wv, WQKVB + 2 * D_ * D_, D_ * D_ / 4);
  f2b4_kernel<<<1024, 256, 0, stream>>>(Wo, WOB,                 D_ * D_ / 4);

  gemm_bt_kernel<false><<<dim3(64, 24), 256, 0, stream>>>(
      XB, WQKVB, BQKV, QKV, B_ * T_, 3 * D_, D_);

  rope_qk_kernel<<<16384, 256, 0, stream>>>(QKV, Qb, Kb);
  vt_kernel<<<dim3(T_ / 64, B_ * H_), 256, 0, stream>>>(QKV, VTb);

  attn_kernel<<<1024, 256, 0, stream>>>(Qb, Kb, VTb, ATTO);

  gemm_bt_kernel<true><<<dim3(64, 8), 256, 0, stream>>>(
      ATTO, WOB, bo, d_out, B_ * T_, D_, D_);

  (void)in_sizes; (void)n_in; (void)out_size; (void)ws_size;
}